// Round 5
// baseline (209.300 us; speedup 1.0000x reference)
//
#include <hip/hip_runtime.h>

typedef float floatx4 __attribute__((ext_vector_type(4)));
typedef __bf16 bf16x8 __attribute__((ext_vector_type(8)));
typedef __bf16 bf16x4 __attribute__((ext_vector_type(4)));

#define MFMA16 __builtin_amdgcn_mfma_f32_16x16x32_bf16

typedef const __attribute__((address_space(1))) void* gas_t;
typedef __attribute__((address_space(3))) void* las_t;
#define GLD16(g, l) __builtin_amdgcn_global_load_lds((gas_t)(g), (las_t)(l), 16, 0, 0)

static __device__ __forceinline__ unsigned short f2bf(float f) {
  union { float f; unsigned int u; } v; v.f = f;
  unsigned int r = v.u + 0x7fffu + ((v.u >> 16) & 1u);
  return (unsigned short)(r >> 16);
}

// ---------------- cast fp32 -> bf16, vectorized x4 ----------------
__global__ void cast_kernel(const float* __restrict__ in,
                            unsigned short* __restrict__ out, int n4) {
  int i = blockIdx.x * blockDim.x + threadIdx.x;
  if (i < n4) {
    float4 v = ((const float4*)in)[i];
    ushort4 o;
    o.x = f2bf(v.x); o.y = f2bf(v.y); o.z = f2bf(v.z); o.w = f2bf(v.w);
    ((ushort4*)out)[i] = o;
  }
}

// ---------------- cast + transpose: in [R][C] fp32 -> out [C][R] bf16 -------
__global__ __launch_bounds__(256) void cast_transpose(
    const float* __restrict__ in, unsigned short* __restrict__ out,
    int R, int C) {
  const int r0 = blockIdx.y * 64, c0 = blockIdx.x * 64;
  const int tid = threadIdx.x;
  __shared__ float tl[64][65];
  const int rr = tid >> 4, cc = (tid & 15) * 4;
#pragma unroll
  for (int i = 0; i < 4; ++i) {
    int row = rr + i * 16;
    float4 v = *(const float4*)(in + (size_t)(r0 + row) * C + c0 + cc);
    tl[row][cc] = v.x; tl[row][cc + 1] = v.y;
    tl[row][cc + 2] = v.z; tl[row][cc + 3] = v.w;
  }
  __syncthreads();
  const int cl = tid >> 2, rbase = (tid & 3) * 16;
  unsigned short o[16];
#pragma unroll
  for (int j = 0; j < 16; ++j) o[j] = f2bf(tl[rbase + j][cl]);
  unsigned short* dst = out + (size_t)(c0 + cl) * R + r0 + rbase;
  *(uint4*)dst = *(uint4*)o;
  *(uint4*)(dst + 8) = *(uint4*)(o + 8);
}

// ---------------- GEMM1: QKV = Xb @ WqkvT^T + bqkv, scatter -----------------
// Qt[bh][d][t] (packed, 0.5*log2e folded), Kc[bh][t][d], Vt[bh][d][t].
// K-region blocks (which==1) compute the tile TRANSPOSED (swap MFMA operands)
// so the K epilogue packs 4 consecutive d per lane -> bf16x4 stores.
__global__ __launch_bounds__(256) void gemm_qkv(
    const unsigned short* __restrict__ A,
    const unsigned short* __restrict__ Bt,
    const float* __restrict__ bias,
    unsigned short* __restrict__ Qt,
    unsigned short* __restrict__ Kc,
    unsigned short* __restrict__ Vt) {
  const int K = 1024;
  const int m0 = blockIdx.y * 128, n0 = blockIdx.x * 128;
  const int tid = threadIdx.x, w = tid >> 6, l = tid & 63;
  const int l16 = l & 15, lq = l >> 4;
  const int wm = w >> 1, wn = w & 1;
  const int which = n0 >> 10;

  __shared__ unsigned short As[128 * 64];
  __shared__ unsigned short Bs[128 * 64];

  floatx4 acc[4][4] = {};

  int sA[4], sB[4];
  unsigned ldso[4];
#pragma unroll
  for (int j = 0; j < 4; ++j) {
    int s = j * 256 + tid;
    int row = s >> 3, blk = (s & 7) ^ (row & 7);
    sA[j] = (m0 + row) * K + blk * 8;
    sB[j] = (n0 + row) * K + blk * 8;
    ldso[j] = (unsigned)(j * 256 + w * 64) * 8;
  }

  if (which != 1) {
    for (int k0 = 0; k0 < K; k0 += 64) {
      __syncthreads();
#pragma unroll
      for (int j = 0; j < 4; ++j) {
        GLD16(A + sA[j] + k0, As + ldso[j]);
        GLD16(Bt + sB[j] + k0, Bs + ldso[j]);
      }
      __syncthreads();
#pragma unroll
      for (int kk = 0; kk < 2; ++kk) {
        bf16x8 af[4], bf[4];
#pragma unroll
        for (int mi = 0; mi < 4; ++mi) {
          int row = wm * 64 + mi * 16 + l16;
          int blk = (kk * 4 + lq) ^ (l16 & 7);
          af[mi] = *(const bf16x8*)(As + row * 64 + blk * 8);
        }
#pragma unroll
        for (int ni = 0; ni < 4; ++ni) {
          int row = wn * 64 + ni * 16 + l16;
          int blk = (kk * 4 + lq) ^ (l16 & 7);
          bf[ni] = *(const bf16x8*)(Bs + row * 64 + blk * 8);
        }
#pragma unroll
        for (int ni = 0; ni < 4; ++ni)
#pragma unroll
          for (int mi = 0; mi < 4; ++mi)
            acc[mi][ni] = MFMA16(af[mi], bf[ni], acc[mi][ni], 0, 0, 0);
      }
    }
    // D[m=t][n=col]; lane: col = ..+l16, t rows = lq*4+r (packed along t)
    float bv[4];
#pragma unroll
    for (int ni = 0; ni < 4; ++ni) bv[ni] = bias[n0 + wn * 64 + ni * 16 + l16];
#pragma unroll
    for (int mi = 0; mi < 4; ++mi) {
#pragma unroll
      for (int ni = 0; ni < 4; ++ni) {
        int col = n0 + wn * 64 + ni * 16 + l16;
        int c1 = col & 1023;
        int h = c1 >> 6, dd = c1 & 63;
        int row0 = m0 + wm * 64 + mi * 16 + lq * 4;
        int bb = row0 >> 11, tt0 = row0 & 2047;
        size_t bh = (size_t)(bb * 16 + h);
        if (which == 2) {
          floatx4 vv = acc[mi][ni] + bv[ni];
          *(bf16x4*)(Vt + (bh * 64 + dd) * 2048 + tt0) =
              __builtin_convertvector(vv, bf16x4);
        } else {
          floatx4 vv = (acc[mi][ni] + bv[ni]) * 0.7213475204444817f;
          *(bf16x4*)(Qt + (bh * 64 + dd) * 2048 + tt0) =
              __builtin_convertvector(vv, bf16x4);
        }
      }
    }
  } else {
    for (int k0 = 0; k0 < K; k0 += 64) {
      __syncthreads();
#pragma unroll
      for (int j = 0; j < 4; ++j) {
        GLD16(A + sA[j] + k0, As + ldso[j]);
        GLD16(Bt + sB[j] + k0, Bs + ldso[j]);
      }
      __syncthreads();
#pragma unroll
      for (int kk = 0; kk < 2; ++kk) {
        bf16x8 af[4], bf[4];
#pragma unroll
        for (int mi = 0; mi < 4; ++mi) {
          int row = wm * 64 + mi * 16 + l16;
          int blk = (kk * 4 + lq) ^ (l16 & 7);
          af[mi] = *(const bf16x8*)(As + row * 64 + blk * 8);
        }
#pragma unroll
        for (int ni = 0; ni < 4; ++ni) {
          int row = wn * 64 + ni * 16 + l16;
          int blk = (kk * 4 + lq) ^ (l16 & 7);
          bf[ni] = *(const bf16x8*)(Bs + row * 64 + blk * 8);
        }
#pragma unroll
        for (int ni = 0; ni < 4; ++ni)
#pragma unroll
          for (int mi = 0; mi < 4; ++mi)
            acc[mi][ni] = MFMA16(bf[ni], af[mi], acc[mi][ni], 0, 0, 0);
      }
    }
    // D[n=col][m=t]; lane: t = ..+l16, cols = lq*4+r (packed along d)
#pragma unroll
    for (int mi = 0; mi < 4; ++mi) {
      int t_g = m0 + wm * 64 + mi * 16 + l16;
      int bb = t_g >> 11, tt = t_g & 2047;
#pragma unroll
      for (int ni = 0; ni < 4; ++ni) {
        int col0 = n0 + wn * 64 + ni * 16 + lq * 4;
        floatx4 bv = *(const floatx4*)(bias + col0);
        floatx4 vv = acc[mi][ni] + bv;
        int h = (col0 & 1023) >> 6, dd0 = col0 & 63;
        size_t bh = (size_t)(bb * 16 + h);
        *(bf16x4*)(Kc + (bh * 2048 + tt) * 64 + dd0) =
            __builtin_convertvector(vv, bf16x4);
      }
    }
  }
}

// ---------------- attention: 4 waves, 128 q/block, swizzled Ps, 2 blk/CU ----
__global__ __launch_bounds__(256) void attn_kernel(
    const unsigned short* __restrict__ Qt,
    const unsigned short* __restrict__ Kc,
    const unsigned short* __restrict__ Vt,
    unsigned short* __restrict__ AO) {
  const int T = 2048;
  const int bh = blockIdx.y, q0 = blockIdx.x * 128;
  const int tid = threadIdx.x, w = tid >> 6, l = tid & 63;
  const int l16 = l & 15, lq = l >> 4;

  __shared__ unsigned short Ks[2][64 * 64];   // 16 KB
  __shared__ unsigned short Vs[2][64 * 64];   // 16 KB
  __shared__ unsigned short Ps[4][32 * 64];   // 16 KB, XOR-swizzled 16B blocks

  // Q fragments from Qt[bh][d][t] (scale+log2e pre-folded)
  bf16x8 qf[2][2];
  {
    const unsigned short* qtb = Qt + (size_t)bh * 64 * 2048 + q0 + w * 32;
#pragma unroll
    for (int qs = 0; qs < 2; ++qs) {
      int t = qs * 16 + l16;
#pragma unroll
      for (int c2 = 0; c2 < 2; ++c2)
#pragma unroll
        for (int j = 0; j < 8; ++j) {
          int d = c2 * 32 + lq * 8 + j;
          qf[qs][c2][j] = ((const __bf16*)qtb)[(size_t)d * 2048 + t];
        }
    }
  }

  float l_lane[2] = {0.f, 0.f};
  floatx4 o_acc[4][2] = {};

  const unsigned short* kbase = Kc + (size_t)bh * T * 64;
  const unsigned short* vbase = Vt + (size_t)bh * 64 * T;
  int kro[2], vro[2];
  unsigned ldso[2];
#pragma unroll
  for (int j = 0; j < 2; ++j) {
    int s = j * 256 + tid;
    int row = s >> 3, blk = (s & 7) ^ (row & 7);
    kro[j] = row * 64 + blk * 8;
    vro[j] = row * T + blk * 8;
    ldso[j] = (unsigned)(j * 256 + w * 64) * 8;
  }

  const int swz0 = (0 + lq) ^ (l16 & 7);
  const int swz1 = (4 + lq) ^ (l16 & 7);

#pragma unroll
  for (int j = 0; j < 2; ++j) {
    GLD16(kbase + kro[j], &Ks[0][ldso[j]]);
    GLD16(vbase + vro[j], &Vs[0][ldso[j]]);
  }

  for (int it = 0; it < 32; ++it) {
    __syncthreads();
    if (it + 1 < 32) {
      int kt = (it + 1) * 64, nb = (it + 1) & 1;
#pragma unroll
      for (int j = 0; j < 2; ++j) {
        GLD16(kbase + kt * 64 + kro[j], &Ks[nb][ldso[j]]);
        GLD16(vbase + kt + vro[j], &Vs[nb][ldso[j]]);
      }
    }
    const unsigned short* kb = Ks[it & 1];
    const unsigned short* vb = Vs[it & 1];

    // S^T: D[k_t = ct*16+lq*4+r][q = w*32+qs*16+l16]
    floatx4 st[2][4];
#pragma unroll
    for (int ct = 0; ct < 4; ++ct) {
      const unsigned short* kr = kb + (ct * 16 + l16) * 64;
      bf16x8 kf0 = *(const bf16x8*)(kr + swz0 * 8);
      bf16x8 kf1 = *(const bf16x8*)(kr + swz1 * 8);
#pragma unroll
      for (int qs = 0; qs < 2; ++qs) {
        floatx4 z = {};
        z = MFMA16(kf0, qf[qs][0], z, 0, 0, 0);
        z = MFMA16(kf1, qf[qs][1], z, 0, 0, 0);
        st[qs][ct] = z;
      }
    }

    unsigned short* pw = Ps[w];
#pragma unroll
    for (int qs = 0; qs < 2; ++qs) {
#pragma unroll
      for (int ct = 0; ct < 4; ++ct) {
        floatx4 pv;
        pv[0] = __builtin_amdgcn_exp2f(st[qs][ct][0]);
        pv[1] = __builtin_amdgcn_exp2f(st[qs][ct][1]);
        pv[2] = __builtin_amdgcn_exp2f(st[qs][ct][2]);
        pv[3] = __builtin_amdgcn_exp2f(st[qs][ct][3]);
        l_lane[qs] += (pv[0] + pv[1]) + (pv[2] + pv[3]);
        bf16x4 pb = __builtin_convertvector(pv, bf16x4);
        int blk16 = (ct * 2 + (lq >> 1)) ^ (l16 & 7);
        *(bf16x4*)(pw + (qs * 16 + l16) * 64 + blk16 * 8 + (lq & 1) * 4) = pb;
      }
    }

    // P^T B-fragments (intra-wave LDS round-trip, swizzled reads)
    bf16x8 pf[2][2];
#pragma unroll
    for (int qs = 0; qs < 2; ++qs)
#pragma unroll
      for (int c2 = 0; c2 < 2; ++c2) {
        int blkr = (c2 * 4 + lq) ^ (l16 & 7);
        pf[qs][c2] = *(const bf16x8*)(pw + (qs * 16 + l16) * 64 + blkr * 8);
      }

    // O^T += V^T * P^T
#pragma unroll
    for (int dt = 0; dt < 4; ++dt) {
      const unsigned short* vr = vb + (dt * 16 + l16) * 64;
      bf16x8 vf0 = *(const bf16x8*)(vr + swz0 * 8);
      bf16x8 vf1 = *(const bf16x8*)(vr + swz1 * 8);
#pragma unroll
      for (int qs = 0; qs < 2; ++qs) {
        o_acc[dt][qs] = MFMA16(vf0, pf[qs][0], o_acc[dt][qs], 0, 0, 0);
        o_acc[dt][qs] = MFMA16(vf1, pf[qs][1], o_acc[dt][qs], 0, 0, 0);
      }
    }
  }

  const int b = bh >> 4, h = bh & 15;
#pragma unroll
  for (int qs = 0; qs < 2; ++qs) {
    float ls = l_lane[qs];
    ls += __shfl_xor(ls, 16, 64);
    ls += __shfl_xor(ls, 32, 64);
    float inv = 1.0f / ls;
    int t = q0 + w * 32 + qs * 16 + l16;
#pragma unroll
    for (int dt = 0; dt < 4; ++dt) {
      floatx4 ov = o_acc[dt][qs] * inv;
      bf16x4 ob = __builtin_convertvector(ov, bf16x4);
      *(bf16x4*)(AO + ((size_t)b * 2048 + t) * 1024 + h * 64 + dt * 16 +
                 lq * 4) = ob;
    }
  }
}

// ---------------- GEMM2: out = AO @ WprojT^T + bproj, swapped -> float4 -----
__global__ __launch_bounds__(256) void gemm_proj(
    const unsigned short* __restrict__ A,
    const unsigned short* __restrict__ Bt,
    const float* __restrict__ bias,
    float* __restrict__ out) {
  const int K = 1024, N = 1024;
  const int m0 = blockIdx.y * 128, n0 = blockIdx.x * 64;
  const int tid = threadIdx.x, w = tid >> 6, l = tid & 63;
  const int l16 = l & 15, lq = l >> 4;

  __shared__ unsigned short As[128 * 64];
  __shared__ unsigned short Bs[64 * 64];

  floatx4 acc[2][4] = {};

  int sA[4], sB[2];
  unsigned ldsoA[4], ldsoB[2];
#pragma unroll
  for (int j = 0; j < 4; ++j) {
    int s = j * 256 + tid;
    int row = s >> 3, blk = (s & 7) ^ (row & 7);
    sA[j] = (m0 + row) * K + blk * 8;
    ldsoA[j] = (unsigned)(j * 256 + w * 64) * 8;
  }
#pragma unroll
  for (int j = 0; j < 2; ++j) {
    int s = j * 256 + tid;
    int row = s >> 3, blk = (s & 7) ^ (row & 7);
    sB[j] = (n0 + row) * K + blk * 8;
    ldsoB[j] = (unsigned)(j * 256 + w * 64) * 8;
  }

  for (int k0 = 0; k0 < K; k0 += 64) {
    __syncthreads();
#pragma unroll
    for (int j = 0; j < 4; ++j) GLD16(A + sA[j] + k0, As + ldsoA[j]);
#pragma unroll
    for (int j = 0; j < 2; ++j) GLD16(Bt + sB[j] + k0, Bs + ldsoB[j]);
    __syncthreads();
#pragma unroll
    for (int kk = 0; kk < 2; ++kk) {
      bf16x8 af[2], bf[4];
#pragma unroll
      for (int mi = 0; mi < 2; ++mi) {
        int row = w * 32 + mi * 16 + l16;
        int blk = (kk * 4 + lq) ^ (l16 & 7);
        af[mi] = *(const bf16x8*)(As + row * 64 + blk * 8);
      }
#pragma unroll
      for (int ni = 0; ni < 4; ++ni) {
        int row = ni * 16 + l16;
        int blk = (kk * 4 + lq) ^ (l16 & 7);
        bf[ni] = *(const bf16x8*)(Bs + row * 64 + blk * 8);
      }
      // swapped: D[n][m] -> lane holds 4 consecutive n at fixed m(t)
#pragma unroll
      for (int ni = 0; ni < 4; ++ni)
#pragma unroll
        for (int mi = 0; mi < 2; ++mi)
          acc[mi][ni] = MFMA16(bf[ni], af[mi], acc[mi][ni], 0, 0, 0);
    }
  }

#pragma unroll
  for (int mi = 0; mi < 2; ++mi) {
    int t = m0 + w * 32 + mi * 16 + l16;
#pragma unroll
    for (int ni = 0; ni < 4; ++ni) {
      int col0 = n0 + ni * 16 + lq * 4;
      floatx4 bv = *(const floatx4*)(bias + col0);
      *(floatx4*)(out + (size_t)t * N + col0) = acc[mi][ni] + bv;
    }
  }
}

extern "C" void kernel_launch(void* const* d_in, const int* in_sizes, int n_in,
                              void* d_out, int out_size, void* d_ws,
                              size_t ws_size, hipStream_t stream) {
  const float* x     = (const float*)d_in[0];
  const float* Wqkv  = (const float*)d_in[1];
  const float* bqkv  = (const float*)d_in[2];
  const float* Wproj = (const float*)d_in[3];
  const float* bproj = (const float*)d_in[4];
  float* out = (float*)d_out;

  unsigned short* Xb     = (unsigned short*)d_ws;  // 4096x1024
  unsigned short* Wqkvt  = Xb + 4194304;           // 3072x1024 (transposed)
  unsigned short* Wprojt = Wqkvt + 3145728;        // 1024x1024 (transposed)
  unsigned short* Qtb    = Wprojt + 1048576;       // 32x64x2048 (pre-scaled)
  unsigned short* Kb     = Qtb + 4194304;          // 32x2048x64
  unsigned short* Vtb    = Kb + 4194304;           // 32x64x2048
  unsigned short* AOb    = Vtb + 4194304;          // 4096x1024

  cast_kernel<<<4096, 256, 0, stream>>>(x, Xb, 1048576);
  cast_transpose<<<dim3(48, 16), 256, 0, stream>>>(Wqkv, Wqkvt, 1024, 3072);
  cast_transpose<<<dim3(16, 16), 256, 0, stream>>>(Wproj, Wprojt, 1024, 1024);

  gemm_qkv<<<dim3(24, 32), 256, 0, stream>>>(Xb, Wqkvt, bqkv, Qtb, Kb, Vtb);
  attn_kernel<<<dim3(16, 32), 256, 0, stream>>>(Qtb, Kb, Vtb, AOb);
  gemm_proj<<<dim3(16, 32), 256, 0, stream>>>(AOb, Wprojt, bproj, out);
}